// Round 5
// baseline (339.193 us; speedup 1.0000x reference)
//
#include <hip/hip_runtime.h>
#include <stdint.h>
#include <math.h>

// ---------- types ----------
typedef short s16x8 __attribute__((ext_vector_type(8)));   // 8 bf16 (4 VGPR)
typedef float f32x4 __attribute__((ext_vector_type(4)));
typedef float f32x16 __attribute__((ext_vector_type(16)));
typedef unsigned short u16x8 __attribute__((ext_vector_type(8)));

__device__ __forceinline__ unsigned short f2bf(float f) {
    union { float f; uint32_t u; } x; x.f = f;
    uint32_t r = x.u + 0x7FFFu + ((x.u >> 16) & 1u);   // RNE
    return (unsigned short)(r >> 16);
}

__device__ __forceinline__ float bf2f(unsigned short u) {
    union { uint32_t u; float f; } x; x.u = ((uint32_t)u) << 16;
    return x.f;
}

__device__ __forceinline__ uint32_t cvtpk_bf16(float lo, float hi) {
    uint32_t r;
    asm("v_cvt_pk_bf16_f32 %0, %1, %2" : "=v"(r) : "v"(lo), "v"(hi));
    return r;
}

#define GLD_LDS16(gp, lp) __builtin_amdgcn_global_load_lds( \
    (const __attribute__((address_space(1))) uint32_t*)(gp), \
    (__attribute__((address_space(3))) uint32_t*)(lp), 16, 0, 0)

#define MFMA16x16x32(a, b, c) __builtin_amdgcn_mfma_f32_16x16x32_bf16((a), (b), (c), 0, 0, 0)
#define MFMA32x32x16(a, b, c) __builtin_amdgcn_mfma_f32_32x32x16_bf16((a), (b), (c), 0, 0, 0)

// lane-half exchange
__device__ __forceinline__ void plswap(uint32_t a, uint32_t b, int lh, uint32_t& x, uint32_t& y) {
#if __has_builtin(__builtin_amdgcn_permlane32_swap)
    auto r = __builtin_amdgcn_permlane32_swap(a, b, false, false);
    x = (uint32_t)r[0]; y = (uint32_t)r[1];
#else
    uint32_t as = (uint32_t)__shfl_xor((int)a, 32, 64);
    uint32_t bs = (uint32_t)__shfl_xor((int)b, 32, 64);
    x = lh ? bs : a;
    y = lh ? b : as;
#endif
}

// ---------- convert kernels ----------
__global__ void cvt_x_kernel(const float* __restrict__ x, unsigned short* __restrict__ xb, int n) {
    int i = (blockIdx.x * blockDim.x + threadIdx.x) * 4;
    if (i >= n) return;
    float4 v = *(const float4*)(x + i);
    unsigned short o0 = f2bf(v.x), o1 = f2bf(v.y), o2 = f2bf(v.z), o3 = f2bf(v.w);
    uint64_t packed = (uint64_t)o0 | ((uint64_t)o1 << 16) | ((uint64_t)o2 << 32) | ((uint64_t)o3 << 48);
    *(uint64_t*)(xb + i) = packed;
}

// merged weight convert: Wq,Wk,Wv [16][1024][64] -> WtQKV rows (which*1024+h*64+d), col c;
// Wp [1024][1024] (c,n) -> WtP [n][c]
__global__ void cvt_w_kernel(const float* __restrict__ Wq, const float* __restrict__ Wk,
                             const float* __restrict__ Wv, const float* __restrict__ Wp,
                             unsigned short* __restrict__ WtQKV, unsigned short* __restrict__ WtP) {
    int id = (blockIdx.x * blockDim.x + threadIdx.x) * 4;   // 4 * 1,048,576 total
    int which = id >> 20, rem = id & 1048575;
    const float* src = (which == 0) ? Wq : (which == 1) ? Wk : (which == 2) ? Wv : Wp;
    float4 v = *(const float4*)(src + rem);
    unsigned short* dst;
    if (which < 3) {
        int h = rem >> 16, c = (rem >> 6) & 1023, d = rem & 63;
        dst = WtQKV + (size_t)(which * 1024 + h * 64 + d) * 1024 + c;
    } else {
        int c = rem >> 10, n = rem & 1023;
        dst = WtP + (size_t)n * 1024 + c;
    }
    dst[0] = f2bf(v.x); dst[1024] = f2bf(v.y); dst[2048] = f2bf(v.z); dst[3072] = f2bf(v.w);
}

// ---------- GEMM: C[M][N] = A[M][K] * Bt[N][K]^T ----------
// MODE 0: QKV — cols [0,1024) Q (pre-scaled by C^-0.5*log2e) + [1024,2048) K -> qkv2 [M][2048];
//         cols [2048,3072) -> vT[(b,h,d)][t]
// MODE 1: f32 out + bias
template<int MODE>
__global__ __launch_bounds__(256) void gemm_bt_kernel(
    const unsigned short* __restrict__ A, const unsigned short* __restrict__ Bt,
    void* __restrict__ Cv, unsigned short* __restrict__ vT,
    const float* __restrict__ bias, int M, int N, int K)
{
    constexpr int BK = 64;
    __shared__ __align__(16) unsigned short As[128 * BK];
    __shared__ __align__(16) unsigned short Bs[128 * BK];
    const int t = threadIdx.x, w = t >> 6, l = t & 63, lr = l & 15, lg = l >> 4;
    const int wm = (w >> 1) << 6, wn = (w & 1) << 6;
    const int bm = blockIdx.x << 7, bn = blockIdx.y << 7;
    const unsigned short* Ab = A + (size_t)bm * K;
    const unsigned short* Bb = Bt + (size_t)bn * K;
    f32x4 acc[4][4] = {};
    for (int k0 = 0; k0 < K; k0 += BK) {
        __syncthreads();
        #pragma unroll
        for (int i = 0; i < 4; ++i) {
            int c = i * 256 + t;
            GLD_LDS16(Ab + (size_t)(c >> 3) * K + k0 + ((c & 7) << 3), As + c * 8);
        }
        #pragma unroll
        for (int i = 0; i < 4; ++i) {
            int c = i * 256 + t;
            GLD_LDS16(Bb + (size_t)(c >> 3) * K + k0 + ((c & 7) << 3), Bs + c * 8);
        }
        __syncthreads();
        #pragma unroll
        for (int ks = 0; ks < 2; ++ks) {
            s16x8 af[4], bfr[4];
            #pragma unroll
            for (int mi = 0; mi < 4; ++mi)
                af[mi] = *(const s16x8*)&As[(wm + mi * 16 + lr) * BK + ks * 32 + lg * 8];
            #pragma unroll
            for (int ni = 0; ni < 4; ++ni)
                bfr[ni] = *(const s16x8*)&Bs[(wn + ni * 16 + lr) * BK + ks * 32 + lg * 8];
            #pragma unroll
            for (int mi = 0; mi < 4; ++mi)
                #pragma unroll
                for (int ni = 0; ni < 4; ++ni)
                    acc[mi][ni] = MFMA16x16x32(af[mi], bfr[ni], acc[mi][ni]);
        }
    }
    if (MODE == 1) {
        float* C = (float*)Cv;
        #pragma unroll
        for (int mi = 0; mi < 4; ++mi)
            #pragma unroll
            for (int ni = 0; ni < 4; ++ni) {
                int col = bn + wn + ni * 16 + lr;
                float bv = bias ? bias[col] : 0.0f;
                #pragma unroll
                for (int r = 0; r < 4; ++r) {
                    int row = bm + wm + mi * 16 + lg * 4 + r;
                    C[(size_t)row * N + col] = acc[mi][ni][r] + bv;
                }
            }
    } else {
        unsigned short* Cq = (unsigned short*)Cv;
        const bool isV = (bn >= 2048);                 // block-uniform
        const float sc = (bn < 1024) ? (0.03125f * 1.44269504088896341f) : 1.0f;  // pre-scale Q
        #pragma unroll
        for (int mi = 0; mi < 4; ++mi)
            #pragma unroll
            for (int ni = 0; ni < 4; ++ni) {
                int col = bn + wn + ni * 16 + lr;
                int row0 = bm + wm + mi * 16 + lg * 4;
                if (!isV) {
                    #pragma unroll
                    for (int r = 0; r < 4; ++r)
                        Cq[(size_t)(row0 + r) * 2048 + col] = f2bf(acc[mi][ni][r] * sc);
                } else {
                    int h = (col >> 6) & 15, d = col & 63;
                    size_t vb = ((size_t)((row0 >> 11) * 16 + h) * 64 + d) * 2048 + (row0 & 2047);
                    uint32_t u0 = (uint32_t)f2bf(acc[mi][ni][0]) | ((uint32_t)f2bf(acc[mi][ni][1]) << 16);
                    uint32_t u1 = (uint32_t)f2bf(acc[mi][ni][2]) | ((uint32_t)f2bf(acc[mi][ni][3]) << 16);
                    *(uint32_t*)&vT[vb]     = u0;
                    *(uint32_t*)&vT[vb + 2] = u1;
                }
            }
    }
}

// ---------- flash attention (32x32 MFMA, in-register P, split-KV) ----------
// S^T = mfma(K, Q): col q = lane&31, row s = (r&3)+8*(r>>2)+4*lh (+32*sblk).
// LDS tiles [64 rows][128 B], chunk swizzle: phys = logical ^ (row & 7).
__device__ __forceinline__ void proc32(
    const unsigned short* __restrict__ Ksb, const unsigned short* __restrict__ Vtb,
    const s16x8* qf, f32x16* o, float& m_r, float& l_r,
    int qms, bool domask, int lq, int lh)
{
    f32x16 S[2] = {};
    __builtin_amdgcn_s_setprio(1);
    #pragma unroll
    for (int sblk = 0; sblk < 2; ++sblk)
        #pragma unroll
        for (int kd = 0; kd < 4; ++kd) {
            int row = sblk * 32 + lq;
            s16x8 kf = *(const s16x8*)&Ksb[row * 64 + (((2 * kd + lh) ^ (row & 7)) << 3)];
            S[sblk] = MFMA32x32x16(kf, qf[kd], S[sblk]);
        }
    __builtin_amdgcn_s_setprio(0);
    if (domask) {
        #pragma unroll
        for (int sblk = 0; sblk < 2; ++sblk)
            #pragma unroll
            for (int r = 0; r < 16; ++r) {
                int s_loc = sblk * 32 + (r & 3) + 8 * (r >> 2) + 4 * lh;
                S[sblk][r] = (s_loc <= qms) ? S[sblk][r] : -1e30f;
            }
    }
    // row max: max3-fusable tree (16 v_max3) + 1 shuffle
    float zm = S[0][0];
    #pragma unroll
    for (int r = 1; r < 15; r += 2) zm = fmaxf(fmaxf(zm, S[0][r]), S[0][r + 1]);
    zm = fmaxf(zm, S[0][15]);
    #pragma unroll
    for (int r = 0; r < 16; r += 2) zm = fmaxf(fmaxf(zm, S[1][r]), S[1][r + 1]);
    zm = fmaxf(zm, __shfl_xor(zm, 32, 64));
    const bool defer = (__all(zm <= m_r + 8.0f) != 0);   // T13
    if (!defer) {
        float mn = fmaxf(m_r, zm);
        float alpha = exp2f(m_r - mn);
        m_r = mn;
        l_r *= alpha;
        o[0] *= alpha;
        o[1] *= alpha;
    }
    float rs = 0.0f;
    uint32_t pk[2][8];
    #pragma unroll
    for (int sblk = 0; sblk < 2; ++sblk) {
        #pragma unroll
        for (int r = 0; r < 16; ++r) {
            float pv = exp2f(S[sblk][r] - m_r);
            S[sblk][r] = pv;
            rs += pv;
        }
        #pragma unroll
        for (int hh = 0; hh < 8; ++hh)
            pk[sblk][hh] = cvtpk_bf16(S[sblk][2 * hh], S[sblk][2 * hh + 1]);
    }
    rs += __shfl_xor(rs, 32, 64);
    l_r += rs;
    // pf[ks2]: B-frag P^T, col q = lane&31, k = s = 16*ks2 + 8*lh + j
    s16x8 pf[4];
    #pragma unroll
    for (int ks2 = 0; ks2 < 4; ++ks2) {
        int sb = ks2 >> 1, Bh = 4 * (ks2 & 1);
        uint32_t w0, w1, w2, w3;
        plswap(pk[sb][Bh + 0], pk[sb][Bh + 2], lh, w0, w2);
        plswap(pk[sb][Bh + 1], pk[sb][Bh + 3], lh, w1, w3);
        union { uint32_t u[4]; s16x8 v; } pu;
        pu.u[0] = w0; pu.u[1] = w1; pu.u[2] = w2; pu.u[3] = w3;
        pf[ks2] = pu.v;
    }
    __builtin_amdgcn_s_setprio(1);
    #pragma unroll
    for (int dblk = 0; dblk < 2; ++dblk)
        #pragma unroll
        for (int ks2 = 0; ks2 < 4; ++ks2) {
            int row = dblk * 32 + lq;
            s16x8 vf = *(const s16x8*)&Vtb[row * 64 + (((2 * ks2 + lh) ^ (row & 7)) << 3)];
            o[dblk] = MFMA32x32x16(vf, pf[ks2], o[dblk]);
        }
    __builtin_amdgcn_s_setprio(0);
}

// Block = 256 threads = 4 waves; 2 splits per (b,h,pair p):
// s=0 handles kv tiles [0,mid), s=1 [mid,nkv) — balanced 16-18 tiles each.
// Partial outputs: normalized O per split + (m,l) per row.
__global__ __launch_bounds__(256, 4) void attn_kernel(
    const unsigned short* __restrict__ qkv2, const unsigned short* __restrict__ vT,
    unsigned short* __restrict__ pO0, unsigned short* __restrict__ pO1,
    float2* __restrict__ mlb, int T)
{
    __shared__ __align__(16) unsigned short Ks[2][64 * 64];   // [s][d], swizzled, 16 KB
    __shared__ __align__(16) unsigned short Vt[2][64 * 64];   // [d][s], swizzled, 16 KB

    const int blk = blockIdx.x;
    const int sp = blk & 1, p = (blk >> 1) & 7, h = (blk >> 4) & 15, b = blk >> 8;
    const int q0A = p * 128, q0B = (15 - p) * 128;
    const int nkv = 32 - 2 * p, mid = 16 - p;
    const int lo = sp ? mid : 0, hiK = sp ? nkv : mid;

    const int t = threadIdx.x, w = t >> 6, l = t & 63, lq = l & 31, lh = l >> 5;
    const int cA = q0A + 32 * w, cB = q0B + 32 * w;
    const int lastA = (cA + 31) >> 6, lastB = (cB + 31) >> 6;

    const unsigned short* qbase = qkv2 + (size_t)b * T * 2048;
    const unsigned short* kbase = qbase + 1024 + h * 64;
    const unsigned short* vtb   = vT + (size_t)(b * 16 + h) * 64 * 2048;

    s16x8 qfA[4], qfB[4];
    #pragma unroll
    for (int kd = 0; kd < 4; ++kd) {
        qfA[kd] = *(const s16x8*)(qbase + (size_t)(cA + lq) * 2048 + h * 64 + kd * 16 + lh * 8);
        qfB[kd] = *(const s16x8*)(qbase + (size_t)(cB + lq) * 2048 + h * 64 + kd * 16 + lh * 8);
    }

    f32x16 oA[2] = {}, oB[2] = {};
    float mA = -1e30f, lA = 0.0f, mB = -1e30f, lB = 0.0f;

    auto STAGE = [&](int buf, int s0) {
        #pragma unroll
        for (int i = 0; i < 2; ++i) {
            int c = i * 256 + t, ss = c >> 3, kk = c & 7;
            GLD_LDS16(kbase + (size_t)(s0 + ss) * 2048 + ((kk ^ (ss & 7)) << 3), &Ks[buf][c * 8]);
        }
        #pragma unroll
        for (int i = 0; i < 2; ++i) {
            int c = i * 256 + t, dd = c >> 3, kk = c & 7;
            GLD_LDS16(vtb + (size_t)dd * 2048 + s0 + ((kk ^ (dd & 7)) << 3), &Vt[buf][c * 8]);
        }
    };

    STAGE(0, lo * 64);
    __syncthreads();

    for (int kt = lo; kt < hiK; ++kt) {
        const int cur = (kt - lo) & 1, nxt = cur ^ 1;
        if (kt + 1 < hiK) STAGE(nxt, (kt + 1) * 64);
        if (kt <= lastA)
            proc32(Ks[cur], Vt[cur], qfA, oA, mA, lA, cA + lq - kt * 64, kt == lastA, lq, lh);
        if (kt <= lastB)
            proc32(Ks[cur], Vt[cur], qfB, oB, mB, lB, cB + lq - kt * 64, kt == lastB, lq, lh);
        __syncthreads();
    }

    // epilogue: normalized partial O^T[d][q]; (m,l) per row from lh==0 lanes
    unsigned short* pOs = sp ? pO1 : pO0;
    {
        float invA = (lA > 0.0f) ? 1.0f / lA : 0.0f;
        float invB = (lB > 0.0f) ? 1.0f / lB : 0.0f;
        #pragma unroll
        for (int dblk = 0; dblk < 2; ++dblk)
            #pragma unroll
            for (int r = 0; r < 16; r += 2) {
                int d = dblk * 32 + (r & 3) + 8 * (r >> 2) + 4 * lh;
                size_t cb = (size_t)h * 64 + d;
                uint32_t ua = cvtpk_bf16(oA[dblk][r] * invA, oA[dblk][r + 1] * invA);
                *(uint32_t*)&pOs[(size_t)(b * T + cA + lq) * 1024 + cb] = ua;
                uint32_t ub = cvtpk_bf16(oB[dblk][r] * invB, oB[dblk][r + 1] * invB);
                *(uint32_t*)&pOs[(size_t)(b * T + cB + lq) * 1024 + cb] = ub;
            }
    }
    if (lh == 0) {
        size_t mlBase = ((size_t)(sp * 4 + b) * 16 + h) * 2048;
        mlb[mlBase + cA + lq] = make_float2(mA, lA);
        mlb[mlBase + cB + lq] = make_float2(mB, lB);
    }
}

// combine: out = w0*o0 + w1*o1, w_s = l_s * 2^(m_s - M), normalized
__global__ __launch_bounds__(256) void combine_kernel(
    const unsigned short* __restrict__ pO0, const unsigned short* __restrict__ pO1,
    const float2* __restrict__ mlb, unsigned short* __restrict__ attnO)
{
    int idx = (blockIdx.x * 256 + threadIdx.x) * 8;        // over 8192*1024
    int row = idx >> 10, col = idx & 1023, h = col >> 6;
    int b = row >> 11, r = row & 2047;
    float2 ml0 = mlb[((size_t)(b) * 16 + h) * 2048 + r];
    float2 ml1 = mlb[((size_t)(4 + b) * 16 + h) * 2048 + r];
    float M = fmaxf(ml0.x, ml1.x);
    float w0 = ml0.y * exp2f(ml0.x - M);
    float w1 = ml1.y * exp2f(ml1.x - M);
    float inv = 1.0f / (w0 + w1);
    w0 *= inv; w1 *= inv;
    u16x8 a = *(const u16x8*)&pO0[idx];
    u16x8 c = *(const u16x8*)&pO1[idx];
    uint32_t ou[4];
    #pragma unroll
    for (int j = 0; j < 4; ++j) {
        float f0 = bf2f(a[2 * j]) * w0 + bf2f(c[2 * j]) * w1;
        float f1 = bf2f(a[2 * j + 1]) * w0 + bf2f(c[2 * j + 1]) * w1;
        ou[j] = cvtpk_bf16(f0, f1);
    }
    *(uint4*)&attnO[idx] = make_uint4(ou[0], ou[1], ou[2], ou[3]);
}

// ---------- launch ----------
extern "C" void kernel_launch(void* const* d_in, const int* in_sizes, int n_in,
                              void* d_out, int out_size, void* d_ws, size_t ws_size,
                              hipStream_t stream) {
    const float* x  = (const float*)d_in[0];
    const float* Wq = (const float*)d_in[1];
    const float* Wk = (const float*)d_in[2];
    const float* Wv = (const float*)d_in[3];
    const float* Wp = (const float*)d_in[4];
    const float* bp = (const float*)d_in[5];
    float* out = (float*)d_out;

    const int T = 2048, C = 1024;
    const int BT = in_sizes[0] / C;      // 8192
    const int B  = BT / T;               // 4

    // workspace layout (bytes), total 92,274,688
    char* ws = (char*)d_ws;
    unsigned short* xb    = (unsigned short*)(ws);                        // 16,777,216  (reused: split-0 partial O)
    unsigned short* WtQKV = (unsigned short*)(ws + 16777216);             //  6,291,456  (reused: ml 2 MB)
    unsigned short* WtP   = (unsigned short*)(ws + 23068672);             //  2,097,152
    unsigned short* qkv2  = (unsigned short*)(ws + 25165824);             // 33,554,432 [8192][2048]
    unsigned short* vT    = (unsigned short*)(ws + 58720256);             // 16,777,216 [(b,h,d)][2048]
    unsigned short* attn  = (unsigned short*)(ws + 75497472);             // 16,777,216  (split-1 partial O, then final)
    float2* mlb = (float2*)WtQKV;
    (void)ws_size; (void)n_in; (void)out_size;

    cvt_x_kernel<<<(BT * C / 4 + 255) / 256, 256, 0, stream>>>(x, xb, BT * C);
    cvt_w_kernel<<<4096, 256, 0, stream>>>(Wq, Wk, Wv, Wp, WtQKV, WtP);

    // QKV projection: Q (pre-scaled), K -> qkv2 [8192][2048]; V -> vT transposed
    gemm_bt_kernel<0><<<dim3(BT / 128, 3072 / 128), 256, 0, stream>>>(
        xb, WtQKV, qkv2, vT, nullptr, BT, 3072, C);

    // flash attention, split-KV: 2 splits x 8 pairs x 16 heads x B
    attn_kernel<<<B * 16 * 8 * 2, 256, 0, stream>>>(qkv2, vT, xb, attn, mlb, T);
    combine_kernel<<<BT * C / (256 * 8), 256, 0, stream>>>(xb, attn, mlb, attn);

    gemm_bt_kernel<1><<<dim3(BT / 128, 1024 / 128), 256, 0, stream>>>(
        attn, WtP, out, nullptr, bp, BT, 1024, C);
}

// Round 6
// 213.563 us; speedup vs baseline: 1.5883x; 1.5883x over previous
//
#include <hip/hip_runtime.h>
#include <stdint.h>
#include <math.h>

// ---------- types ----------
typedef short s16x8 __attribute__((ext_vector_type(8)));   // 8 bf16 (4 VGPR)
typedef float f32x4 __attribute__((ext_vector_type(4)));
typedef float f32x16 __attribute__((ext_vector_type(16)));

__device__ __forceinline__ unsigned short f2bf(float f) {
    union { float f; uint32_t u; } x; x.f = f;
    uint32_t r = x.u + 0x7FFFu + ((x.u >> 16) & 1u);   // RNE
    return (unsigned short)(r >> 16);
}

__device__ __forceinline__ uint32_t cvtpk_bf16(float lo, float hi) {
    uint32_t r;
    asm("v_cvt_pk_bf16_f32 %0, %1, %2" : "=v"(r) : "v"(lo), "v"(hi));
    return r;
}

#define GLD_LDS16(gp, lp) __builtin_amdgcn_global_load_lds( \
    (const __attribute__((address_space(1))) uint32_t*)(gp), \
    (__attribute__((address_space(3))) uint32_t*)(lp), 16, 0, 0)

#define MFMA16x16x32(a, b, c) __builtin_amdgcn_mfma_f32_16x16x32_bf16((a), (b), (c), 0, 0, 0)
#define MFMA32x32x16(a, b, c) __builtin_amdgcn_mfma_f32_32x32x16_bf16((a), (b), (c), 0, 0, 0)

// lane-half exchange
__device__ __forceinline__ void plswap(uint32_t a, uint32_t b, int lh, uint32_t& x, uint32_t& y) {
#if __has_builtin(__builtin_amdgcn_permlane32_swap)
    auto r = __builtin_amdgcn_permlane32_swap(a, b, false, false);
    x = (uint32_t)r[0]; y = (uint32_t)r[1];
#else
    uint32_t as = (uint32_t)__shfl_xor((int)a, 32, 64);
    uint32_t bs = (uint32_t)__shfl_xor((int)b, 32, 64);
    x = lh ? bs : a;
    y = lh ? b : as;
#endif
}

// ---------- convert kernels ----------
__global__ void cvt_x_kernel(const float* __restrict__ x, unsigned short* __restrict__ xb, int n) {
    int i = (blockIdx.x * blockDim.x + threadIdx.x) * 4;
    if (i >= n) return;
    float4 v = *(const float4*)(x + i);
    unsigned short o0 = f2bf(v.x), o1 = f2bf(v.y), o2 = f2bf(v.z), o3 = f2bf(v.w);
    uint64_t packed = (uint64_t)o0 | ((uint64_t)o1 << 16) | ((uint64_t)o2 << 32) | ((uint64_t)o3 << 48);
    *(uint64_t*)(xb + i) = packed;
}

// merged weight convert: Wq,Wk,Wv [16][1024][64] -> WtQKV rows (which*1024+h*64+d), col c;
// Wp [1024][1024] (c,n) -> WtP [n][c]
__global__ void cvt_w_kernel(const float* __restrict__ Wq, const float* __restrict__ Wk,
                             const float* __restrict__ Wv, const float* __restrict__ Wp,
                             unsigned short* __restrict__ WtQKV, unsigned short* __restrict__ WtP) {
    int id = (blockIdx.x * blockDim.x + threadIdx.x) * 4;   // 4 * 1,048,576 total
    int which = id >> 20, rem = id & 1048575;
    const float* src = (which == 0) ? Wq : (which == 1) ? Wk : (which == 2) ? Wv : Wp;
    float4 v = *(const float4*)(src + rem);
    unsigned short* dst;
    if (which < 3) {
        int h = rem >> 16, c = (rem >> 6) & 1023, d = rem & 63;
        dst = WtQKV + (size_t)(which * 1024 + h * 64 + d) * 1024 + c;
    } else {
        int c = rem >> 10, n = rem & 1023;
        dst = WtP + (size_t)n * 1024 + c;
    }
    dst[0] = f2bf(v.x); dst[1024] = f2bf(v.y); dst[2048] = f2bf(v.z); dst[3072] = f2bf(v.w);
}

// ---------- GEMM: C[M][N] = A[M][K] * Bt[N][K]^T ----------
// MODE 0: QKV — cols [0,1024) Q (pre-scaled by C^-0.5*log2e) + [1024,2048) K -> qkv2 [M][2048];
//         cols [2048,3072) -> vT[(b,h,d)][t]
// MODE 1: f32 out + bias
template<int MODE>
__global__ __launch_bounds__(256) void gemm_bt_kernel(
    const unsigned short* __restrict__ A, const unsigned short* __restrict__ Bt,
    void* __restrict__ Cv, unsigned short* __restrict__ vT,
    const float* __restrict__ bias, int M, int N, int K)
{
    constexpr int BK = 64;
    __shared__ __align__(16) unsigned short As[128 * BK];
    __shared__ __align__(16) unsigned short Bs[128 * BK];
    const int t = threadIdx.x, w = t >> 6, l = t & 63, lr = l & 15, lg = l >> 4;
    const int wm = (w >> 1) << 6, wn = (w & 1) << 6;
    const int bm = blockIdx.x << 7, bn = blockIdx.y << 7;
    const unsigned short* Ab = A + (size_t)bm * K;
    const unsigned short* Bb = Bt + (size_t)bn * K;
    f32x4 acc[4][4] = {};
    for (int k0 = 0; k0 < K; k0 += BK) {
        __syncthreads();
        #pragma unroll
        for (int i = 0; i < 4; ++i) {
            int c = i * 256 + t;
            GLD_LDS16(Ab + (size_t)(c >> 3) * K + k0 + ((c & 7) << 3), As + c * 8);
        }
        #pragma unroll
        for (int i = 0; i < 4; ++i) {
            int c = i * 256 + t;
            GLD_LDS16(Bb + (size_t)(c >> 3) * K + k0 + ((c & 7) << 3), Bs + c * 8);
        }
        __syncthreads();
        #pragma unroll
        for (int ks = 0; ks < 2; ++ks) {
            s16x8 af[4], bfr[4];
            #pragma unroll
            for (int mi = 0; mi < 4; ++mi)
                af[mi] = *(const s16x8*)&As[(wm + mi * 16 + lr) * BK + ks * 32 + lg * 8];
            #pragma unroll
            for (int ni = 0; ni < 4; ++ni)
                bfr[ni] = *(const s16x8*)&Bs[(wn + ni * 16 + lr) * BK + ks * 32 + lg * 8];
            #pragma unroll
            for (int mi = 0; mi < 4; ++mi)
                #pragma unroll
                for (int ni = 0; ni < 4; ++ni)
                    acc[mi][ni] = MFMA16x16x32(af[mi], bfr[ni], acc[mi][ni]);
        }
    }
    if (MODE == 1) {
        float* C = (float*)Cv;
        #pragma unroll
        for (int mi = 0; mi < 4; ++mi)
            #pragma unroll
            for (int ni = 0; ni < 4; ++ni) {
                int col = bn + wn + ni * 16 + lr;
                float bv = bias ? bias[col] : 0.0f;
                #pragma unroll
                for (int r = 0; r < 4; ++r) {
                    int row = bm + wm + mi * 16 + lg * 4 + r;
                    C[(size_t)row * N + col] = acc[mi][ni][r] + bv;
                }
            }
    } else {
        unsigned short* Cq = (unsigned short*)Cv;
        const bool isV = (bn >= 2048);                 // block-uniform
        const float sc = (bn < 1024) ? (0.03125f * 1.44269504088896341f) : 1.0f;  // pre-scale Q
        #pragma unroll
        for (int mi = 0; mi < 4; ++mi)
            #pragma unroll
            for (int ni = 0; ni < 4; ++ni) {
                int col = bn + wn + ni * 16 + lr;
                int row0 = bm + wm + mi * 16 + lg * 4;
                if (!isV) {
                    #pragma unroll
                    for (int r = 0; r < 4; ++r)
                        Cq[(size_t)(row0 + r) * 2048 + col] = f2bf(acc[mi][ni][r] * sc);
                } else {
                    int h = (col >> 6) & 15, d = col & 63;
                    size_t vb = ((size_t)((row0 >> 11) * 16 + h) * 64 + d) * 2048 + (row0 & 2047);
                    uint32_t u0 = (uint32_t)f2bf(acc[mi][ni][0]) | ((uint32_t)f2bf(acc[mi][ni][1]) << 16);
                    uint32_t u1 = (uint32_t)f2bf(acc[mi][ni][2]) | ((uint32_t)f2bf(acc[mi][ni][3]) << 16);
                    *(uint32_t*)&vT[vb]     = u0;
                    *(uint32_t*)&vT[vb + 2] = u1;
                }
            }
    }
}

// ---------- flash attention (32x32 MFMA, in-register P, 8-wave blocks) ----------
// S^T = mfma(K, Q): col q = lane&31, row s = (r&3)+8*(r>>2)+4*lh (+32*sblk).
// LDS layout (K and V tiles, 64 rows x 128 B): 256-B super-rows (row pair u = s>>1),
// 16 slots of 16 B; slot = (chunk + 8*(s&1)) ^ (u & 15). 2-way bank aliasing = free.
__device__ __forceinline__ void proc32(
    const unsigned short* __restrict__ Ksb, const unsigned short* __restrict__ Vtb,
    const s16x8* qf, f32x16* o, float& m_r, float& l_r,
    int qms, bool domask, int lq, int lh)
{
    const int ub = lq >> 1;                 // (row>>1) & 15
    const int vb8 = (lq & 1) << 3;
    f32x16 S[2] = {};
    __builtin_amdgcn_s_setprio(1);
    #pragma unroll
    for (int sblk = 0; sblk < 2; ++sblk)
        #pragma unroll
        for (int kd = 0; kd < 4; ++kd) {
            s16x8 kf = *(const s16x8*)((const char*)Ksb + (sblk * 16 + ub) * 256
                                       + ((((2 * kd + lh) + vb8) ^ ub) << 4));
            S[sblk] = MFMA32x32x16(kf, qf[kd], S[sblk]);
        }
    __builtin_amdgcn_s_setprio(0);
    if (domask) {
        #pragma unroll
        for (int sblk = 0; sblk < 2; ++sblk)
            #pragma unroll
            for (int r = 0; r < 16; ++r) {
                int s_loc = sblk * 32 + (r & 3) + 8 * (r >> 2) + 4 * lh;
                S[sblk][r] = (s_loc <= qms) ? S[sblk][r] : -1e30f;
            }
    }
    // row max: max3-fusable tree + 1 shuffle (lane^32 = same q, other s-half)
    float zm = S[0][0];
    #pragma unroll
    for (int r = 1; r < 15; r += 2) zm = fmaxf(fmaxf(zm, S[0][r]), S[0][r + 1]);
    zm = fmaxf(zm, S[0][15]);
    #pragma unroll
    for (int r = 0; r < 16; r += 2) zm = fmaxf(fmaxf(zm, S[1][r]), S[1][r + 1]);
    zm = fmaxf(zm, __shfl_xor(zm, 32, 64));
    const bool defer = (__all(zm <= m_r + 8.0f) != 0);   // T13
    if (!defer) {
        float mn = fmaxf(m_r, zm);
        float alpha = exp2f(m_r - mn);
        m_r = mn;
        l_r *= alpha;
        o[0] *= alpha;
        o[1] *= alpha;
    }
    float rs = 0.0f;
    uint32_t pk[2][8];
    #pragma unroll
    for (int sblk = 0; sblk < 2; ++sblk) {
        #pragma unroll
        for (int r = 0; r < 16; ++r) {
            float pv = exp2f(S[sblk][r] - m_r);
            S[sblk][r] = pv;
            rs += pv;
        }
        #pragma unroll
        for (int hh = 0; hh < 8; ++hh)
            pk[sblk][hh] = cvtpk_bf16(S[sblk][2 * hh], S[sblk][2 * hh + 1]);
    }
    rs += __shfl_xor(rs, 32, 64);
    l_r += rs;
    // pf[ks2]: B-frag P^T, col q = lane&31, k = s = 16*ks2 + 8*lh + j
    s16x8 pf[4];
    #pragma unroll
    for (int ks2 = 0; ks2 < 4; ++ks2) {
        int sb = ks2 >> 1, Bh = 4 * (ks2 & 1);
        uint32_t w0, w1, w2, w3;
        plswap(pk[sb][Bh + 0], pk[sb][Bh + 2], lh, w0, w2);
        plswap(pk[sb][Bh + 1], pk[sb][Bh + 3], lh, w1, w3);
        union { uint32_t u[4]; s16x8 v; } pu;
        pu.u[0] = w0; pu.u[1] = w1; pu.u[2] = w2; pu.u[3] = w3;
        pf[ks2] = pu.v;
    }
    __builtin_amdgcn_s_setprio(1);
    #pragma unroll
    for (int dblk = 0; dblk < 2; ++dblk)
        #pragma unroll
        for (int ks2 = 0; ks2 < 4; ++ks2) {
            s16x8 vf = *(const s16x8*)((const char*)Vtb + (dblk * 16 + ub) * 256
                                       + ((((2 * ks2 + lh) + vb8) ^ ub) << 4));
            o[dblk] = MFMA32x32x16(vf, pf[ks2], o[dblk]);
        }
    __builtin_amdgcn_s_setprio(0);
}

// Block = 512 threads = 8 waves; block p: pair of 128-row q-tiles {p, 15-p} of one (b,h).
// Waves 0-3: 32-row slices of tile A; waves 4-7: of tile B. One stage shared by all 8 waves.
__global__ __launch_bounds__(512, 4) void attn_kernel(
    const unsigned short* __restrict__ qkv2, const unsigned short* __restrict__ vT,
    unsigned short* __restrict__ attnO, int T)
{
    __shared__ __align__(16) unsigned short Ks[2][64 * 64];   // 8 KB each buf, super-row layout
    __shared__ __align__(16) unsigned short Vt[2][64 * 64];

    const int blk = blockIdx.x;
    const int p = blk & 7, h = (blk >> 3) & 15, b = blk >> 7;
    const int q0A = p * 128, q0B = (15 - p) * 128;
    const int nkv = 32 - 2 * p;

    const int t = threadIdx.x, w = t >> 6, l = t & 63, lq = l & 31, lh = l >> 5;
    const int c0 = ((w >> 2) ? q0B : q0A) + 32 * (w & 3);
    const int lastT = (c0 + 31) >> 6;     // inclusive kv-tile bound for this wave

    const unsigned short* qbase = qkv2 + (size_t)b * T * 2048;
    const unsigned short* kbase = qbase + 1024 + h * 64;
    const unsigned short* vtb   = vT + (size_t)(b * 16 + h) * 64 * 2048;

    s16x8 qf[4];
    #pragma unroll
    for (int kd = 0; kd < 4; ++kd)
        qf[kd] = *(const s16x8*)(qbase + (size_t)(c0 + lq) * 2048 + h * 64 + kd * 16 + lh * 8);

    f32x16 o[2] = {};
    float m_r = -1e30f, l_r = 0.0f;

    // staging: thread t fills LDS 16B-chunk t (0..511) of each tile.
    // dest chunk i: u=i>>4, slot=i&15; x=slot^(u&15); row=2u+(x>>3), chunk=x&7.
    const int su = t >> 4, sx = (t & 15) ^ (su & 15);
    const int srow = 2 * su + (sx >> 3), schunk = (sx & 7) << 3;
    auto STAGE = [&](int buf, int s0) {
        GLD_LDS16(kbase + (size_t)(s0 + srow) * 2048 + schunk, &Ks[buf][t * 8]);
        GLD_LDS16(vtb + (size_t)srow * 2048 + s0 + schunk, &Vt[buf][t * 8]);
    };

    STAGE(0, 0);
    __syncthreads();

    for (int kt = 0; kt < nkv; ++kt) {
        const int cur = kt & 1, nxt = cur ^ 1;
        if (kt + 1 < nkv) STAGE(nxt, (kt + 1) * 64);
        if (kt <= lastT)
            proc32(Ks[cur], Vt[cur], qf, o, m_r, l_r, c0 + lq - kt * 64, kt == lastT, lq, lh);
        __syncthreads();
    }

    // epilogue: O^T[d][q] — lane owns column q = c0+lq; d = (r&3)+8*(r>>2)+4*lh (+32*dblk)
    {
        float inv = 1.0f / l_r;
        #pragma unroll
        for (int dblk = 0; dblk < 2; ++dblk)
            #pragma unroll
            for (int r = 0; r < 16; r += 2) {
                int d = dblk * 32 + (r & 3) + 8 * (r >> 2) + 4 * lh;
                uint32_t ua = cvtpk_bf16(o[dblk][r] * inv, o[dblk][r + 1] * inv);
                *(uint32_t*)&attnO[(size_t)(b * T + c0 + lq) * 1024 + h * 64 + d] = ua;
            }
    }
}

// ---------- launch ----------
extern "C" void kernel_launch(void* const* d_in, const int* in_sizes, int n_in,
                              void* d_out, int out_size, void* d_ws, size_t ws_size,
                              hipStream_t stream) {
    const float* x  = (const float*)d_in[0];
    const float* Wq = (const float*)d_in[1];
    const float* Wk = (const float*)d_in[2];
    const float* Wv = (const float*)d_in[3];
    const float* Wp = (const float*)d_in[4];
    const float* bp = (const float*)d_in[5];
    float* out = (float*)d_out;

    const int T = 2048, C = 1024;
    const int BT = in_sizes[0] / C;      // 8192
    const int B  = BT / T;               // 4

    // workspace layout (bytes), total 92,274,688
    char* ws = (char*)d_ws;
    unsigned short* xb    = (unsigned short*)(ws);                        // 16,777,216
    unsigned short* WtQKV = (unsigned short*)(ws + 16777216);             //  6,291,456
    unsigned short* WtP   = (unsigned short*)(ws + 23068672);             //  2,097,152
    unsigned short* qkv2  = (unsigned short*)(ws + 25165824);             // 33,554,432 [8192][2048]
    unsigned short* vT    = (unsigned short*)(ws + 58720256);             // 16,777,216 [(b,h,d)][2048]
    unsigned short* attn  = (unsigned short*)(ws + 75497472);             // 16,777,216
    (void)ws_size; (void)n_in; (void)out_size;

    cvt_x_kernel<<<(BT * C / 4 + 255) / 256, 256, 0, stream>>>(x, xb, BT * C);
    cvt_w_kernel<<<4096, 256, 0, stream>>>(Wq, Wk, Wv, Wp, WtQKV, WtP);

    // QKV projection: Q (pre-scaled), K -> qkv2 [8192][2048]; V -> vT transposed
    gemm_bt_kernel<0><<<dim3(BT / 128, 3072 / 128), 256, 0, stream>>>(
        xb, WtQKV, qkv2, vT, nullptr, BT, 3072, C);

    // flash attention: 8 pairs x 16 heads x B blocks, 512 threads each
    attn_kernel<<<B * 16 * 8, 512, 0, stream>>>(qkv2, vT, attn, T);

    gemm_bt_kernel<1><<<dim3(BT / 128, 1024 / 128), 256, 0, stream>>>(
        attn, WtP, out, nullptr, bp, BT, 1024, C);
}

// Round 7
// 198.368 us; speedup vs baseline: 1.7099x; 1.0766x over previous
//
#include <hip/hip_runtime.h>
#include <stdint.h>
#include <math.h>

// ---------- types ----------
typedef short s16x8 __attribute__((ext_vector_type(8)));   // 8 bf16 (4 VGPR)
typedef float f32x4 __attribute__((ext_vector_type(4)));
typedef float f32x16 __attribute__((ext_vector_type(16)));

__device__ __forceinline__ unsigned short f2bf(float f) {
    union { float f; uint32_t u; } x; x.f = f;
    uint32_t r = x.u + 0x7FFFu + ((x.u >> 16) & 1u);   // RNE
    return (unsigned short)(r >> 16);
}

__device__ __forceinline__ uint32_t cvtpk_bf16(float lo, float hi) {
    uint32_t r;
    asm("v_cvt_pk_bf16_f32 %0, %1, %2" : "=v"(r) : "v"(lo), "v"(hi));
    return r;
}

#define GLD_LDS16(gp, lp) __builtin_amdgcn_global_load_lds( \
    (const __attribute__((address_space(1))) uint32_t*)(gp), \
    (__attribute__((address_space(3))) uint32_t*)(lp), 16, 0, 0)

#define MFMA16x16x32(a, b, c) __builtin_amdgcn_mfma_f32_16x16x32_bf16((a), (b), (c), 0, 0, 0)
#define MFMA32x32x16(a, b, c) __builtin_amdgcn_mfma_f32_32x32x16_bf16((a), (b), (c), 0, 0, 0)

// lane-half exchange
__device__ __forceinline__ void plswap(uint32_t a, uint32_t b, int lh, uint32_t& x, uint32_t& y) {
#if __has_builtin(__builtin_amdgcn_permlane32_swap)
    auto r = __builtin_amdgcn_permlane32_swap(a, b, false, false);
    x = (uint32_t)r[0]; y = (uint32_t)r[1];
#else
    uint32_t as = (uint32_t)__shfl_xor((int)a, 32, 64);
    uint32_t bs = (uint32_t)__shfl_xor((int)b, 32, 64);
    x = lh ? bs : a;
    y = lh ? b : as;
#endif
}

// ---------- convert kernels ----------
__global__ void cvt_x_kernel(const float* __restrict__ x, unsigned short* __restrict__ xb, int n) {
    int i = (blockIdx.x * blockDim.x + threadIdx.x) * 4;
    if (i >= n) return;
    float4 v = *(const float4*)(x + i);
    unsigned short o0 = f2bf(v.x), o1 = f2bf(v.y), o2 = f2bf(v.z), o3 = f2bf(v.w);
    uint64_t packed = (uint64_t)o0 | ((uint64_t)o1 << 16) | ((uint64_t)o2 << 32) | ((uint64_t)o3 << 48);
    *(uint64_t*)(xb + i) = packed;
}

// merged weight convert: Wq,Wk,Wv [16][1024][64] -> WtQKV rows (which*1024+h*64+d), col c;
// Wp [1024][1024] (c,n) -> WtP [n][c]
__global__ void cvt_w_kernel(const float* __restrict__ Wq, const float* __restrict__ Wk,
                             const float* __restrict__ Wv, const float* __restrict__ Wp,
                             unsigned short* __restrict__ WtQKV, unsigned short* __restrict__ WtP) {
    int id = (blockIdx.x * blockDim.x + threadIdx.x) * 4;   // 4 * 1,048,576 total
    int which = id >> 20, rem = id & 1048575;
    const float* src = (which == 0) ? Wq : (which == 1) ? Wk : (which == 2) ? Wv : Wp;
    float4 v = *(const float4*)(src + rem);
    unsigned short* dst;
    if (which < 3) {
        int h = rem >> 16, c = (rem >> 6) & 1023, d = rem & 63;
        dst = WtQKV + (size_t)(which * 1024 + h * 64 + d) * 1024 + c;
    } else {
        int c = rem >> 10, n = rem & 1023;
        dst = WtP + (size_t)n * 1024 + c;
    }
    dst[0] = f2bf(v.x); dst[1024] = f2bf(v.y); dst[2048] = f2bf(v.z); dst[3072] = f2bf(v.w);
}

// ---------- QKV GEMM: deep-pipeline counted-vmcnt (T3+T4+T5) ----------
// C[M][N] = A[M][K] * Bt[N][K]^T, M=8192, N=3072, K=1024.
// BM=128, BN=256, BK=32; 8 waves (2 M x 4 N), 64x64 per wave; 3 LDS buffers (72 KB).
// Tile j stages tile j+2 (A:1 + B:2 gloads/thread); one vmcnt(3) per tile keeps
// the next tile's loads in flight across barriers (never drains to 0 mid-loop).
// LDS layout per panel [R][32] bf16, 64 B/row: super-row u=r>>2 (256 B, 16 slots
// of 16 B), slot = (chunk + 4*(r&3)) ^ (u&15) -> 16 lanes hit 16 distinct slots
// (2 lanes/bank = free). Staged linearly via inverse-permuted global source.
__global__ __launch_bounds__(512, 4) void gemm_qkv_kernel(
    const unsigned short* __restrict__ A, const unsigned short* __restrict__ Bt,
    unsigned short* __restrict__ qkv2, unsigned short* __restrict__ vT)
{
    constexpr int K = 1024, NT = 32;     // K-tiles of 32
    __shared__ __align__(16) unsigned short LA[3][128 * 32];   // 8 KB each
    __shared__ __align__(16) unsigned short LB[3][256 * 32];   // 16 KB each

    const int t = threadIdx.x, w = t >> 6, l = t & 63, lr = l & 15, lg = l >> 4;
    const int wm2 = w >> 2, wn4 = w & 3;

    // XCD-bijective swizzle: 768 blocks, 96 per XCD (x-fastest within chunk)
    int bid = blockIdx.x;
    int swz = (bid & 7) * 96 + (bid >> 3);
    const int bm = (swz & 63) << 7, bn = (swz >> 6) << 8;

    const unsigned short* Ab = A + (size_t)bm * K;
    const unsigned short* Bb = Bt + (size_t)bn * K;

    // stage geometry: dest chunk i -> (row, k-elem) via inverse swizzle
    int sArow, sAce, sBrow[2], sBce[2];
    {
        int u = t >> 4, x = (t & 15) ^ (u & 15);
        sArow = 4 * u + (x >> 2); sAce = (x & 3) << 3;
        #pragma unroll
        for (int i2 = 0; i2 < 2; ++i2) {
            int i = t + i2 * 512;
            int ub = i >> 4, xb2 = (i & 15) ^ (ub & 15);
            sBrow[i2] = 4 * ub + (xb2 >> 2); sBce[i2] = (xb2 & 3) << 3;
        }
    }

    // fragment byte offsets (swizzled reads), constant across K-loop
    int aoff[4], boff[4];
    #pragma unroll
    for (int m = 0; m < 4; ++m) {
        int u = 16 * wm2 + 4 * m + (lr >> 2);
        aoff[m] = u * 256 + (((lg + 4 * (lr & 3)) ^ (u & 15)) << 4);
    }
    #pragma unroll
    for (int n = 0; n < 4; ++n) {
        int u = 16 * wn4 + 4 * n + (lr >> 2);
        boff[n] = u * 256 + (((lg + 4 * (lr & 3)) ^ (u & 15)) << 4);
    }

    f32x4 acc[4][4] = {};

    // prologue: stage tiles 0 and 1; wait for tile 0 only (tile 1 stays in flight)
    GLD_LDS16(Ab + (size_t)sArow * K + 0 + sAce, &LA[0][t * 8]);
    #pragma unroll
    for (int i2 = 0; i2 < 2; ++i2)
        GLD_LDS16(Bb + (size_t)sBrow[i2] * K + 0 + sBce[i2], &LB[0][(t + i2 * 512) * 8]);
    GLD_LDS16(Ab + (size_t)sArow * K + 32 + sAce, &LA[1][t * 8]);
    #pragma unroll
    for (int i2 = 0; i2 < 2; ++i2)
        GLD_LDS16(Bb + (size_t)sBrow[i2] * K + 32 + sBce[i2], &LB[1][(t + i2 * 512) * 8]);
    asm volatile("s_waitcnt vmcnt(3)" ::: "memory");
    __builtin_amdgcn_sched_barrier(0);
    __builtin_amdgcn_s_barrier();

    int cur = 0;
    for (int j = 0; j < NT; ++j) {
        const int dst = (cur >= 1) ? cur - 1 : cur + 2;      // (j+2) % 3
        const bool st = (j + 2 < NT);
        const int k2 = (j + 2) << 5;
        // issue this tile's fragment reads
        s16x8 af[4], bfr[4];
        #pragma unroll
        for (int m = 0; m < 4; ++m)
            af[m] = *(const s16x8*)((const char*)LA[cur] + aoff[m]);
        #pragma unroll
        for (int n = 0; n < 4; ++n)
            bfr[n] = *(const s16x8*)((const char*)LB[cur] + boff[n]);
        // issue prefetch for tile j+2
        if (st) {
            GLD_LDS16(Ab + (size_t)sArow * K + k2 + sAce, &LA[dst][t * 8]);
            #pragma unroll
            for (int i2 = 0; i2 < 2; ++i2)
                GLD_LDS16(Bb + (size_t)sBrow[i2] * K + k2 + sBce[i2], &LB[dst][(t + i2 * 512) * 8]);
        }
        __builtin_amdgcn_s_barrier();
        asm volatile("s_waitcnt lgkmcnt(0)" ::: "memory");
        __builtin_amdgcn_sched_barrier(0);
        __builtin_amdgcn_s_setprio(1);
        #pragma unroll
        for (int m = 0; m < 4; ++m)
            #pragma unroll
            for (int n = 0; n < 4; ++n)
                acc[m][n] = MFMA16x16x32(af[m], bfr[n], acc[m][n]);
        __builtin_amdgcn_s_setprio(0);
        if (j + 1 < NT) {
            if (st) { asm volatile("s_waitcnt vmcnt(3)" ::: "memory"); }
            else    { asm volatile("s_waitcnt vmcnt(0)" ::: "memory"); }
            __builtin_amdgcn_sched_barrier(0);
        }
        __builtin_amdgcn_s_barrier();
        cur = (cur == 2) ? 0 : cur + 1;
    }

    // epilogue: cols [0,1024) Q scaled, [1024,2048) K -> qkv2; [2048,3072) -> vT
    const bool isV = (bn >= 2048);
    const float sc = (bn < 1024) ? (0.03125f * 1.44269504088896341f) : 1.0f;
    #pragma unroll
    for (int mi = 0; mi < 4; ++mi)
        #pragma unroll
        for (int ni = 0; ni < 4; ++ni) {
            int col = bn + wn4 * 64 + ni * 16 + lr;
            int row0 = bm + wm2 * 64 + mi * 16 + lg * 4;
            if (!isV) {
                #pragma unroll
                for (int r = 0; r < 4; ++r)
                    qkv2[(size_t)(row0 + r) * 2048 + col] = f2bf(acc[mi][ni][r] * sc);
            } else {
                int h = (col >> 6) & 15, d = col & 63;
                size_t vb = ((size_t)((row0 >> 11) * 16 + h) * 64 + d) * 2048 + (row0 & 2047);
                uint32_t u0 = (uint32_t)f2bf(acc[mi][ni][0]) | ((uint32_t)f2bf(acc[mi][ni][1]) << 16);
                uint32_t u1 = (uint32_t)f2bf(acc[mi][ni][2]) | ((uint32_t)f2bf(acc[mi][ni][3]) << 16);
                *(uint32_t*)&vT[vb]     = u0;
                *(uint32_t*)&vT[vb + 2] = u1;
            }
        }
}

// ---------- proj GEMM: C[M][N] = A[M][K] * Bt[N][K]^T, f32 out + bias ----------
__global__ __launch_bounds__(256) void gemm_proj_kernel(
    const unsigned short* __restrict__ A, const unsigned short* __restrict__ Bt,
    float* __restrict__ C, const float* __restrict__ bias, int M, int N, int K)
{
    constexpr int BK = 64;
    __shared__ __align__(16) unsigned short As[128 * BK];
    __shared__ __align__(16) unsigned short Bs[128 * BK];
    const int t = threadIdx.x, w = t >> 6, l = t & 63, lr = l & 15, lg = l >> 4;
    const int wm = (w >> 1) << 6, wn = (w & 1) << 6;
    const int bm = blockIdx.x << 7, bn = blockIdx.y << 7;
    const unsigned short* Ab = A + (size_t)bm * K;
    const unsigned short* Bb = Bt + (size_t)bn * K;
    f32x4 acc[4][4] = {};
    for (int k0 = 0; k0 < K; k0 += BK) {
        __syncthreads();
        #pragma unroll
        for (int i = 0; i < 4; ++i) {
            int c = i * 256 + t;
            GLD_LDS16(Ab + (size_t)(c >> 3) * K + k0 + ((c & 7) << 3), As + c * 8);
        }
        #pragma unroll
        for (int i = 0; i < 4; ++i) {
            int c = i * 256 + t;
            GLD_LDS16(Bb + (size_t)(c >> 3) * K + k0 + ((c & 7) << 3), Bs + c * 8);
        }
        __syncthreads();
        #pragma unroll
        for (int ks = 0; ks < 2; ++ks) {
            s16x8 af[4], bfr[4];
            #pragma unroll
            for (int mi = 0; mi < 4; ++mi)
                af[mi] = *(const s16x8*)&As[(wm + mi * 16 + lr) * BK + ks * 32 + lg * 8];
            #pragma unroll
            for (int ni = 0; ni < 4; ++ni)
                bfr[ni] = *(const s16x8*)&Bs[(wn + ni * 16 + lr) * BK + ks * 32 + lg * 8];
            #pragma unroll
            for (int mi = 0; mi < 4; ++mi)
                #pragma unroll
                for (int ni = 0; ni < 4; ++ni)
                    acc[mi][ni] = MFMA16x16x32(af[mi], bfr[ni], acc[mi][ni]);
        }
    }
    #pragma unroll
    for (int mi = 0; mi < 4; ++mi)
        #pragma unroll
        for (int ni = 0; ni < 4; ++ni) {
            int col = bn + wn + ni * 16 + lr;
            float bv = bias[col];
            #pragma unroll
            for (int r = 0; r < 4; ++r) {
                int row = bm + wm + mi * 16 + lg * 4 + r;
                C[(size_t)row * N + col] = acc[mi][ni][r] + bv;
            }
        }
}

// ---------- flash attention (32x32 MFMA, in-register P, 8-wave blocks) ----------
// S^T = mfma(K, Q): col q = lane&31, row s = (r&3)+8*(r>>2)+4*lh (+32*sblk).
// LDS layout (K and V tiles, 64 rows x 128 B): 256-B super-rows (row pair u = s>>1),
// 16 slots of 16 B; slot = (chunk + 8*(s&1)) ^ (u & 15). 2-way bank aliasing = free.
__device__ __forceinline__ void proc32(
    const unsigned short* __restrict__ Ksb, const unsigned short* __restrict__ Vtb,
    const s16x8* qf, f32x16* o, float& m_r, float& l_r,
    int qms, bool domask, int lq, int lh)
{
    const int ub = lq >> 1;                 // (row>>1) & 15
    const int vb8 = (lq & 1) << 3;
    f32x16 S[2] = {};
    __builtin_amdgcn_s_setprio(1);
    #pragma unroll
    for (int sblk = 0; sblk < 2; ++sblk)
        #pragma unroll
        for (int kd = 0; kd < 4; ++kd) {
            s16x8 kf = *(const s16x8*)((const char*)Ksb + (sblk * 16 + ub) * 256
                                       + ((((2 * kd + lh) + vb8) ^ ub) << 4));
            S[sblk] = MFMA32x32x16(kf, qf[kd], S[sblk]);
        }
    __builtin_amdgcn_s_setprio(0);
    if (domask) {
        #pragma unroll
        for (int sblk = 0; sblk < 2; ++sblk)
            #pragma unroll
            for (int r = 0; r < 16; ++r) {
                int s_loc = sblk * 32 + (r & 3) + 8 * (r >> 2) + 4 * lh;
                S[sblk][r] = (s_loc <= qms) ? S[sblk][r] : -1e30f;
            }
    }
    // row max: max3-fusable tree + 1 shuffle (lane^32 = same q, other s-half)
    float zm = S[0][0];
    #pragma unroll
    for (int r = 1; r < 15; r += 2) zm = fmaxf(fmaxf(zm, S[0][r]), S[0][r + 1]);
    zm = fmaxf(zm, S[0][15]);
    #pragma unroll
    for (int r = 0; r < 16; r += 2) zm = fmaxf(fmaxf(zm, S[1][r]), S[1][r + 1]);
    zm = fmaxf(zm, __shfl_xor(zm, 32, 64));
    const bool defer = (__all(zm <= m_r + 8.0f) != 0);   // T13
    if (!defer) {
        float mn = fmaxf(m_r, zm);
        float alpha = exp2f(m_r - mn);
        m_r = mn;
        l_r *= alpha;
        o[0] *= alpha;
        o[1] *= alpha;
    }
    float rs = 0.0f;
    uint32_t pk[2][8];
    #pragma unroll
    for (int sblk = 0; sblk < 2; ++sblk) {
        #pragma unroll
        for (int r = 0; r < 16; ++r) {
            float pv = exp2f(S[sblk][r] - m_r);
            S[sblk][r] = pv;
            rs += pv;
        }
        #pragma unroll
        for (int hh = 0; hh < 8; ++hh)
            pk[sblk][hh] = cvtpk_bf16(S[sblk][2 * hh], S[sblk][2 * hh + 1]);
    }
    rs += __shfl_xor(rs, 32, 64);
    l_r += rs;
    // pf[ks2]: B-frag P^T, col q = lane&31, k = s = 16*ks2 + 8*lh + j
    s16x8 pf[4];
    #pragma unroll
    for (int ks2 = 0; ks2 < 4; ++ks2) {
        int sb = ks2 >> 1, Bh = 4 * (ks2 & 1);
        uint32_t w0, w1, w2, w3;
        plswap(pk[sb][Bh + 0], pk[sb][Bh + 2], lh, w0, w2);
        plswap(pk[sb][Bh + 1], pk[sb][Bh + 3], lh, w1, w3);
        union { uint32_t u[4]; s16x8 v; } pu;
        pu.u[0] = w0; pu.u[1] = w1; pu.u[2] = w2; pu.u[3] = w3;
        pf[ks2] = pu.v;
    }
    __builtin_amdgcn_s_setprio(1);
    #pragma unroll
    for (int dblk = 0; dblk < 2; ++dblk)
        #pragma unroll
        for (int ks2 = 0; ks2 < 4; ++ks2) {
            s16x8 vf = *(const s16x8*)((const char*)Vtb + (dblk * 16 + ub) * 256
                                       + ((((2 * ks2 + lh) + vb8) ^ ub) << 4));
            o[dblk] = MFMA32x32x16(vf, pf[ks2], o[dblk]);
        }
    __builtin_amdgcn_s_setprio(0);
}

// Block = 512 threads = 8 waves; block p: pair of 128-row q-tiles {p, 15-p} of one (b,h).
// Waves 0-3: 32-row slices of tile A; waves 4-7: of tile B. One stage shared by all 8 waves.
__global__ __launch_bounds__(512, 4) void attn_kernel(
    const unsigned short* __restrict__ qkv2, const unsigned short* __restrict__ vT,
    unsigned short* __restrict__ attnO, int T)
{
    __shared__ __align__(16) unsigned short Ks[2][64 * 64];   // 8 KB each buf, super-row layout
    __shared__ __align__(16) unsigned short Vt[2][64 * 64];

    const int blk = blockIdx.x;
    const int p = blk & 7, h = (blk >> 3) & 15, b = blk >> 7;
    const int q0A = p * 128, q0B = (15 - p) * 128;
    const int nkv = 32 - 2 * p;

    const int t = threadIdx.x, w = t >> 6, l = t & 63, lq = l & 31, lh = l >> 5;
    const int c0 = ((w >> 2) ? q0B : q0A) + 32 * (w & 3);
    const int lastT = (c0 + 31) >> 6;     // inclusive kv-tile bound for this wave

    const unsigned short* qbase = qkv2 + (size_t)b * T * 2048;
    const unsigned short* kbase = qbase + 1024 + h * 64;
    const unsigned short* vtb   = vT + (size_t)(b * 16 + h) * 64 * 2048;

    s16x8 qf[4];
    #pragma unroll
    for (int kd = 0; kd < 4; ++kd)
        qf[kd] = *(const s16x8*)(qbase + (size_t)(c0 + lq) * 2048 + h * 64 + kd * 16 + lh * 8);

    f32x16 o[2] = {};
    float m_r = -1e30f, l_r = 0.0f;

    // staging: thread t fills LDS 16B-chunk t (0..511) of each tile.
    // dest chunk i: u=i>>4, slot=i&15; x=slot^(u&15); row=2u+(x>>3), chunk=x&7.
    const int su = t >> 4, sx = (t & 15) ^ (su & 15);
    const int srow = 2 * su + (sx >> 3), schunk = (sx & 7) << 3;
    auto STAGE = [&](int buf, int s0) {
        GLD_LDS16(kbase + (size_t)(s0 + srow) * 2048 + schunk, &Ks[buf][t * 8]);
        GLD_LDS16(vtb + (size_t)srow * 2048 + s0 + schunk, &Vt[buf][t * 8]);
    };

    STAGE(0, 0);
    __syncthreads();

    for (int kt = 0; kt < nkv; ++kt) {
        const int cur = kt & 1, nxt = cur ^ 1;
        if (kt + 1 < nkv) STAGE(nxt, (kt + 1) * 64);
        if (kt <= lastT)
            proc32(Ks[cur], Vt[cur], qf, o, m_r, l_r, c0 + lq - kt * 64, kt == lastT, lq, lh);
        __syncthreads();
    }

    // epilogue: O^T[d][q] — lane owns column q = c0+lq; d = (r&3)+8*(r>>2)+4*lh (+32*dblk)
    {
        float inv = 1.0f / l_r;
        #pragma unroll
        for (int dblk = 0; dblk < 2; ++dblk)
            #pragma unroll
            for (int r = 0; r < 16; r += 2) {
                int d = dblk * 32 + (r & 3) + 8 * (r >> 2) + 4 * lh;
                uint32_t ua = cvtpk_bf16(o[dblk][r] * inv, o[dblk][r + 1] * inv);
                *(uint32_t*)&attnO[(size_t)(b * T + c0 + lq) * 1024 + h * 64 + d] = ua;
            }
    }
}

// ---------- launch ----------
extern "C" void kernel_launch(void* const* d_in, const int* in_sizes, int n_in,
                              void* d_out, int out_size, void* d_ws, size_t ws_size,
                              hipStream_t stream) {
    const float* x  = (const float*)d_in[0];
    const float* Wq = (const float*)d_in[1];
    const float* Wk = (const float*)d_in[2];
    const float* Wv = (const float*)d_in[3];
    const float* Wp = (const float*)d_in[4];
    const float* bp = (const float*)d_in[5];
    float* out = (float*)d_out;

    const int T = 2048, C = 1024;
    const int BT = in_sizes[0] / C;      // 8192
    const int B  = BT / T;               // 4

    // workspace layout (bytes), total 92,274,688
    char* ws = (char*)d_ws;
    unsigned short* xb    = (unsigned short*)(ws);                        // 16,777,216
    unsigned short* WtQKV = (unsigned short*)(ws + 16777216);             //  6,291,456
    unsigned short* WtP   = (unsigned short*)(ws + 23068672);             //  2,097,152
    unsigned short* qkv2  = (unsigned short*)(ws + 25165824);             // 33,554,432 [8192][2048]
    unsigned short* vT    = (unsigned short*)(ws + 58720256);             // 16,777,216 [(b,h,d)][2048]
    unsigned short* attn  = (unsigned short*)(ws + 75497472);             // 16,777,216
    (void)ws_size; (void)n_in; (void)out_size;

    cvt_x_kernel<<<(BT * C / 4 + 255) / 256, 256, 0, stream>>>(x, xb, BT * C);
    cvt_w_kernel<<<4096, 256, 0, stream>>>(Wq, Wk, Wv, Wp, WtQKV, WtP);

    // QKV projection: Q (pre-scaled), K -> qkv2 [8192][2048]; V -> vT transposed
    gemm_qkv_kernel<<<768, 512, 0, stream>>>(xb, WtQKV, qkv2, vT);

    // flash attention: 8 pairs x 16 heads x B blocks, 512 threads each
    attn_kernel<<<B * 16 * 8, 512, 0, stream>>>(qkv2, vT, attn, T);

    gemm_proj_kernel<<<dim3(BT / 128, 1024 / 128), 256, 0, stream>>>(
        attn, WtP, out, bp, BT, 1024, C);
}